// Round 2
// baseline (336.085 us; speedup 1.0000x reference)
//
#include <hip/hip_runtime.h>
#include <hip/hip_bf16.h>

// Typed-relation MHA, MI355X.  B=2 L=2048 HID=512 NH=8 DH=64 T=3.
// Pipeline: cast -> QKV gemm -> V-transpose -> qt gemm -> flash attn -> out gemm.
// All GEMMs: bf16 MFMA 16x16x32, fragments loaded directly from global (L2-hot),
// weights pre-transposed so B-fragments (8 contiguous K for fixed N) are 16B loads.

typedef __attribute__((ext_vector_type(4))) float f32x4;
typedef __attribute__((ext_vector_type(8))) short bf16x8;

static __device__ __forceinline__ unsigned short f2bf(float x) {
  __hip_bfloat16 h = __float2bfloat16(x);
  return *reinterpret_cast<unsigned short*>(&h);
}
static __device__ __forceinline__ bf16x8 ld8(const unsigned short* p) {
  return *reinterpret_cast<const bf16x8*>(p);
}

// ---------------- P0: casts + transposes of weights ----------------
__global__ void prep_cast(const float* __restrict__ query,
                          const float* __restrict__ Wq, const float* __restrict__ Wk,
                          const float* __restrict__ Wv, const float* __restrict__ Wo,
                          const float* __restrict__ tw,
                          unsigned short* __restrict__ q_bf,
                          unsigned short* __restrict__ WT_bf,    // [3][512 n][512 k]
                          unsigned short* __restrict__ WoT_bf,   // [512 n][512 k]
                          unsigned short* __restrict__ twT_bf) { // [3][8][64 e][64 d]
  const int stride = gridDim.x * blockDim.x;
  const int tid = blockIdx.x * blockDim.x + threadIdx.x;
  for (int i = tid; i < 4096 * 512; i += stride) q_bf[i] = f2bf(query[i]);
  for (int i = tid; i < 3 * 512 * 512; i += stride) {
    int m = i >> 18, r = i & ((1 << 18) - 1), n = r >> 9, k = r & 511;
    const float* W = (m == 0) ? Wq : (m == 1 ? Wk : Wv);
    WT_bf[i] = f2bf(W[k * 512 + n]);
  }
  for (int i = tid; i < 512 * 512; i += stride) {
    int n = i >> 9, k = i & 511;
    WoT_bf[i] = f2bf(Wo[k * 512 + n]);
  }
  for (int i = tid; i < 3 * 8 * 64 * 64; i += stride) {
    int th = i >> 12, r = i & 4095, e = r >> 6, d = r & 63;
    twT_bf[i] = f2bf(tw[(th << 12) + (d << 6) + e]);
  }
}

// ---------------- P1: fused QKV GEMM  C[4096,1536] ----------------
// tile 128x64, 4 waves (2x2), per-wave 64x32 = mf4 x nf2 frags, BK=32.
__global__ __launch_bounds__(256) void qkv_gemm(
    const unsigned short* __restrict__ Abf,  // query_bf [4096][512]
    const unsigned short* __restrict__ WT,   // [3][512 n][512 k]
    const float* __restrict__ bq, const float* __restrict__ bk, const float* __restrict__ bv,
    unsigned short* __restrict__ qh, unsigned short* __restrict__ kh,
    unsigned short* __restrict__ vh) {       // each [B,H,L,DH]
  const int m0 = blockIdx.x * 128;
  const int n0g = blockIdx.y * 64;
  const int mat = n0g >> 9;        // 0=q 1=k 2=v
  const int ncol0 = n0g & 511;     // multiple of 64
  const int h = ncol0 >> 6;
  const int wave = threadIdx.x >> 6, lane = threadIdx.x & 63;
  const int mw = wave >> 1, nw = wave & 1;
  const int lhi = lane >> 4, llo = lane & 15;
  const unsigned short* WTm = WT + mat * (512 * 512);
  f32x4 acc[4][2];
#pragma unroll
  for (int i = 0; i < 4; i++)
#pragma unroll
    for (int j = 0; j < 2; j++) acc[i][j] = (f32x4){0.f, 0.f, 0.f, 0.f};
  const int arow = m0 + mw * 64 + llo;
  const int brow = ncol0 + nw * 32 + llo;
  for (int k0 = 0; k0 < 512; k0 += 32) {
    const int kk = k0 + lhi * 8;
    bf16x8 a[4], b[2];
#pragma unroll
    for (int mf = 0; mf < 4; mf++) a[mf] = ld8(Abf + (arow + 16 * mf) * 512 + kk);
#pragma unroll
    for (int nf = 0; nf < 2; nf++) b[nf] = ld8(WTm + (brow + 16 * nf) * 512 + kk);
#pragma unroll
    for (int mf = 0; mf < 4; mf++)
#pragma unroll
      for (int nf = 0; nf < 2; nf++)
        acc[mf][nf] = __builtin_amdgcn_mfma_f32_16x16x32_bf16(a[mf], b[nf], acc[mf][nf], 0, 0, 0);
  }
  const float* bias = (mat == 0) ? bq : (mat == 1 ? bk : bv);
  unsigned short* dst = (mat == 0) ? qh : (mat == 1 ? kh : vh);
  const float scale = (mat == 0) ? 0.125f : 1.0f;  // DH^-0.5
#pragma unroll
  for (int mf = 0; mf < 4; mf++) {
#pragma unroll
    for (int nf = 0; nf < 2; nf++) {
      const int d = nw * 32 + 16 * nf + llo;  // 0..63 within head
      const float bv_ = bias[ncol0 + d];
#pragma unroll
      for (int r = 0; r < 4; r++) {
        const int row = m0 + mw * 64 + 16 * mf + lhi * 4 + r;  // C-layout row
        const int bb = row >> 11, l = row & 2047;
        const float val = (acc[mf][nf][r] + bv_) * scale;
        dst[(((bb * 8 + h) * 2048) + l) * 64 + d] = f2bf(val);
      }
    }
  }
}

// ---------------- P2: V transpose [B,H,L,D] -> [B,H,D,L] ----------------
__global__ __launch_bounds__(256) void transpose_v(const unsigned short* __restrict__ vh,
                                                   unsigned short* __restrict__ vhT) {
  __shared__ unsigned short tile[64][65];  // +1 pad: conflict-free column reads
  const int bh = blockIdx.x;        // 16
  const int l0 = blockIdx.y * 64;   // 32 tiles
  const unsigned short* src = vh + bh * 2048 * 64;
  unsigned short* dst = vhT + bh * 64 * 2048;
  const int t = threadIdx.x;
#pragma unroll
  for (int p = 0; p < 2; p++) {
    const int idx = t + p * 256;
    const int l = idx >> 3, d0 = (idx & 7) * 8;
    bf16x8 v = ld8(src + (l0 + l) * 64 + d0);
#pragma unroll
    for (int j = 0; j < 8; j++) tile[l][d0 + j] = (unsigned short)v[j];
  }
  __syncthreads();
#pragma unroll
  for (int p = 0; p < 2; p++) {
    const int d = (t >> 3) + p * 32;
    const int ls = (t & 7) * 8;
    bf16x8 o;
#pragma unroll
    for (int j = 0; j < 8; j++) o[j] = (short)tile[ls + j][d];
    *reinterpret_cast<bf16x8*>(dst + d * 2048 + l0 + ls) = o;
  }
}

// ---------------- P3: qt = qh @ W_t  (per b,h,t) -> [B,H,T,L,D] ----------------
__global__ __launch_bounds__(256) void qt_gemm(const unsigned short* __restrict__ qh,   // [B,H,L,D]
                                               const unsigned short* __restrict__ twT,  // [3][8][e][d]
                                               unsigned short* __restrict__ qt) {       // [B,H,T,L,D]
  const int l0 = blockIdx.x * 128;
  const int bh = blockIdx.y;  // 16
  const int t = blockIdx.z;   // 3
  const int h = bh & 7;
  const int wave = threadIdx.x >> 6, lane = threadIdx.x & 63;
  const int lhi = lane >> 4, llo = lane & 15;
  const unsigned short* A = qh + bh * 2048 * 64;
  const unsigned short* Bt = twT + (t * 8 + h) * 64 * 64;
  const int r0 = l0 + wave * 32;
  f32x4 acc[2][4];
#pragma unroll
  for (int i = 0; i < 2; i++)
#pragma unroll
    for (int j = 0; j < 4; j++) acc[i][j] = (f32x4){0.f, 0.f, 0.f, 0.f};
  bf16x8 a[2][2], b[4][2];
#pragma unroll
  for (int mf = 0; mf < 2; mf++)
#pragma unroll
    for (int kk = 0; kk < 2; kk++)
      a[mf][kk] = ld8(A + (r0 + 16 * mf + llo) * 64 + kk * 32 + lhi * 8);
#pragma unroll
  for (int nf = 0; nf < 4; nf++)
#pragma unroll
    for (int kk = 0; kk < 2; kk++)
      b[nf][kk] = ld8(Bt + (16 * nf + llo) * 64 + kk * 32 + lhi * 8);
#pragma unroll
  for (int mf = 0; mf < 2; mf++)
#pragma unroll
    for (int nf = 0; nf < 4; nf++)
#pragma unroll
      for (int kk = 0; kk < 2; kk++)
        acc[mf][nf] = __builtin_amdgcn_mfma_f32_16x16x32_bf16(a[mf][kk], b[nf][kk], acc[mf][nf], 0, 0, 0);
  unsigned short* dst = qt + (bh * 3 + t) * 2048 * 64;
#pragma unroll
  for (int mf = 0; mf < 2; mf++)
#pragma unroll
    for (int nf = 0; nf < 4; nf++)
#pragma unroll
      for (int r = 0; r < 4; r++)
        dst[(r0 + 16 * mf + lhi * 4 + r) * 64 + 16 * nf + llo] = f2bf(acc[mf][nf][r]);
}

// ---------------- P4: flash attention ----------------
// grid (L/16, B); block 512 = 8 waves = 8 heads. QT=16 rows/wave, KT=32.
// pbuf is strictly per-wave -> NO barriers needed (same-wave DS ops are in-order).
__global__ __launch_bounds__(512) void flash_attn(
    const unsigned short* __restrict__ qt,   // [B,H,3,L,D] (scaled)
    const unsigned short* __restrict__ kh,   // [B,H,L,D]
    const unsigned short* __restrict__ vhT,  // [B,H,D,L]
    const int* __restrict__ tids,            // [B,L,L]
    const float* __restrict__ bias,          // [B,1,1,L]
    unsigned short* __restrict__ xout) {     // [B,H,L,D]
  __shared__ unsigned short pbuf[8][16][40];  // per-wave P roundtrip, 16B-aligned rows
  const int b = blockIdx.y;
  const int q0 = blockIdx.x * 16;
  const int h = threadIdx.x >> 6;
  const int lane = threadIdx.x & 63;
  const int lhi = lane >> 4, llo = lane & 15;
  const int bh = b * 8 + h;
  const unsigned short* khb = kh + bh * 2048 * 64;
  const unsigned short* vtb = vhT + bh * 64 * 2048;
  const int* tb = tids + b * 2048 * 2048;
  const float* bb = bias + b * 2048;
  const float LOG2E = 1.4426950408889634f;

  bf16x8 qf[3][2];
#pragma unroll
  for (int t = 0; t < 3; t++)
#pragma unroll
    for (int kk = 0; kk < 2; kk++)
      qf[t][kk] = ld8(qt + ((bh * 3 + t) * 2048 + q0 + llo) * 64 + kk * 32 + lhi * 8);

  f32x4 oacc[4];
#pragma unroll
  for (int i = 0; i < 4; i++) oacc[i] = (f32x4){0.f, 0.f, 0.f, 0.f};
  float mrow[4], lrow[4];
#pragma unroll
  for (int r = 0; r < 4; r++) { mrow[r] = -1e30f; lrow[r] = 0.f; }

  for (int kt = 0; kt < 2048; kt += 32) {
    bf16x8 kf[2][2];
#pragma unroll
    for (int nf = 0; nf < 2; nf++)
#pragma unroll
      for (int kk = 0; kk < 2; kk++)
        kf[nf][kk] = ld8(khb + (kt + 16 * nf + llo) * 64 + kk * 32 + lhi * 8);
    int tv[2][4];
#pragma unroll
    for (int nf = 0; nf < 2; nf++)
#pragma unroll
      for (int r = 0; r < 4; r++)
        tv[nf][r] = tb[(q0 + 4 * lhi + r) * 2048 + kt + 16 * nf + llo];

    f32x4 logit[2];
#pragma unroll
    for (int t = 0; t < 3; t++) {
      f32x4 s0 = (f32x4){0.f, 0.f, 0.f, 0.f}, s1 = (f32x4){0.f, 0.f, 0.f, 0.f};
      s0 = __builtin_amdgcn_mfma_f32_16x16x32_bf16(qf[t][0], kf[0][0], s0, 0, 0, 0);
      s0 = __builtin_amdgcn_mfma_f32_16x16x32_bf16(qf[t][1], kf[0][1], s0, 0, 0, 0);
      s1 = __builtin_amdgcn_mfma_f32_16x16x32_bf16(qf[t][0], kf[1][0], s1, 0, 0, 0);
      s1 = __builtin_amdgcn_mfma_f32_16x16x32_bf16(qf[t][1], kf[1][1], s1, 0, 0, 0);
      if (t == 0) { logit[0] = s0; logit[1] = s1; }
      else {
#pragma unroll
        for (int r = 0; r < 4; r++) {
          logit[0][r] = (tv[0][r] == t) ? s0[r] : logit[0][r];
          logit[1][r] = (tv[1][r] == t) ? s1[r] : logit[1][r];
        }
      }
    }
    const float b0 = bb[kt + llo], b1 = bb[kt + 16 + llo];
#pragma unroll
    for (int r = 0; r < 4; r++) { logit[0][r] += b0; logit[1][r] += b1; }

    float pmax[4], fr[4], rs[4];
#pragma unroll
    for (int r = 0; r < 4; r++) pmax[r] = fmaxf(logit[0][r], logit[1][r]);
#pragma unroll
    for (int xm = 1; xm < 16; xm <<= 1)
#pragma unroll
      for (int r = 0; r < 4; r++) pmax[r] = fmaxf(pmax[r], __shfl_xor(pmax[r], xm, 16));
#pragma unroll
    for (int r = 0; r < 4; r++) {
      const float mn = fmaxf(mrow[r], pmax[r]);
      fr[r] = exp2f((mrow[r] - mn) * LOG2E);
      mrow[r] = mn;
      rs[r] = 0.f;
    }
#pragma unroll
    for (int nf = 0; nf < 2; nf++)
#pragma unroll
      for (int r = 0; r < 4; r++) {
        const float p = exp2f((logit[nf][r] - mrow[r]) * LOG2E);
        logit[nf][r] = p;
        rs[r] += p;
      }
#pragma unroll
    for (int xm = 1; xm < 16; xm <<= 1)
#pragma unroll
      for (int r = 0; r < 4; r++) rs[r] += __shfl_xor(rs[r], xm, 16);
#pragma unroll
    for (int r = 0; r < 4; r++) lrow[r] = lrow[r] * fr[r] + rs[r];
#pragma unroll
    for (int nfd = 0; nfd < 4; nfd++)
#pragma unroll
      for (int r = 0; r < 4; r++) oacc[nfd][r] *= fr[r];

    // P (C-layout) -> LDS -> A-fragment layout (per-wave buffer, no barrier)
#pragma unroll
    for (int nf = 0; nf < 2; nf++)
#pragma unroll
      for (int r = 0; r < 4; r++)
        pbuf[h][4 * lhi + r][16 * nf + llo] = f2bf(logit[nf][r]);
    const bf16x8 pa = *reinterpret_cast<const bf16x8*>(&pbuf[h][llo][lhi * 8]);
    bf16x8 vf[4];
#pragma unroll
    for (int nfd = 0; nfd < 4; nfd++)
      vf[nfd] = ld8(vtb + (16 * nfd + llo) * 2048 + kt + lhi * 8);
#pragma unroll
    for (int nfd = 0; nfd < 4; nfd++)
      oacc[nfd] = __builtin_amdgcn_mfma_f32_16x16x32_bf16(pa, vf[nfd], oacc[nfd], 0, 0, 0);
  }
  float inv[4];
#pragma unroll
  for (int r = 0; r < 4; r++) inv[r] = 1.f / lrow[r];
#pragma unroll
  for (int nfd = 0; nfd < 4; nfd++)
#pragma unroll
    for (int r = 0; r < 4; r++)
      xout[(bh * 2048 + q0 + 4 * lhi + r) * 64 + 16 * nfd + llo] = f2bf(oacc[nfd][r] * inv[r]);
}

// ---------------- P5: out = x @ Wo + bo  (f32 out) ----------------
__global__ __launch_bounds__(256) void out_gemm(const unsigned short* __restrict__ xbf,  // [B,H,L,D]
                                                const unsigned short* __restrict__ WoT,  // [512 n][512 k]
                                                const float* __restrict__ bo,
                                                float* __restrict__ out) {  // [4096][512]
  const int m0 = blockIdx.x * 128;
  const int n0 = blockIdx.y * 64;
  const int wave = threadIdx.x >> 6, lane = threadIdx.x & 63;
  const int mw = wave >> 1, nw = wave & 1;
  const int lhi = lane >> 4, llo = lane & 15;
  f32x4 acc[4][2];
#pragma unroll
  for (int i = 0; i < 4; i++)
#pragma unroll
    for (int j = 0; j < 2; j++) acc[i][j] = (f32x4){0.f, 0.f, 0.f, 0.f};
  const int arow = m0 + mw * 64 + llo;
  const int bb = arow >> 11, l = arow & 2047;  // block rows never cross b boundary
  const int brow = n0 + nw * 32 + llo;
  for (int k0 = 0; k0 < 512; k0 += 32) {
    const int kk = k0 + lhi * 8;
    const int hk = kk >> 6, d0 = kk & 63;
    bf16x8 a[4], b[2];
#pragma unroll
    for (int mf = 0; mf < 4; mf++)
      a[mf] = ld8(xbf + ((bb * 8 + hk) * 2048 + l + 16 * mf) * 64 + d0);
#pragma unroll
    for (int nf = 0; nf < 2; nf++) b[nf] = ld8(WoT + (brow + 16 * nf) * 512 + kk);
#pragma unroll
    for (int mf = 0; mf < 4; mf++)
#pragma unroll
      for (int nf = 0; nf < 2; nf++)
        acc[mf][nf] = __builtin_amdgcn_mfma_f32_16x16x32_bf16(a[mf], b[nf], acc[mf][nf], 0, 0, 0);
  }
#pragma unroll
  for (int mf = 0; mf < 4; mf++)
#pragma unroll
    for (int nf = 0; nf < 2; nf++) {
      const int col = n0 + nw * 32 + 16 * nf + llo;
      const float bv_ = bo[col];
#pragma unroll
      for (int r = 0; r < 4; r++) {
        const int row = m0 + mw * 64 + 16 * mf + lhi * 4 + r;
        out[row * 512 + col] = acc[mf][nf][r] + bv_;
      }
    }
}

extern "C" void kernel_launch(void* const* d_in, const int* in_sizes, int n_in,
                              void* d_out, int out_size, void* d_ws, size_t ws_size,
                              hipStream_t stream) {
  const float* query = (const float*)d_in[0];
  const float* bias  = (const float*)d_in[1];
  const int*   tids  = (const int*)d_in[2];
  const float* Wq = (const float*)d_in[3];
  const float* bq = (const float*)d_in[4];
  const float* Wk = (const float*)d_in[5];
  const float* bk = (const float*)d_in[6];
  const float* Wv = (const float*)d_in[7];
  const float* bv = (const float*)d_in[8];
  const float* Wo = (const float*)d_in[9];
  const float* bo = (const float*)d_in[10];
  const float* tw = (const float*)d_in[11];
  float* out = (float*)d_out;

  // workspace layout (bf16 buffers), ~41 MB total
  char* ws = (char*)d_ws;
  size_t off = 0;
  auto take = [&](size_t bytes) { char* p = ws + off; off = (off + bytes + 255) & ~(size_t)255; return p; };
  unsigned short* q_bf   = (unsigned short*)take((size_t)4096 * 512 * 2);
  unsigned short* WT_bf  = (unsigned short*)take((size_t)3 * 512 * 512 * 2);
  unsigned short* WoT_bf = (unsigned short*)take((size_t)512 * 512 * 2);
  unsigned short* twT_bf = (unsigned short*)take((size_t)3 * 8 * 64 * 64 * 2);
  unsigned short* qh_bf  = (unsigned short*)take((size_t)2 * 8 * 2048 * 64 * 2);
  unsigned short* kh_bf  = (unsigned short*)take((size_t)2 * 8 * 2048 * 64 * 2);
  unsigned short* vh_bf  = (unsigned short*)take((size_t)2 * 8 * 2048 * 64 * 2);
  unsigned short* vhT_bf = (unsigned short*)take((size_t)2 * 8 * 64 * 2048 * 2);
  unsigned short* qt_bf  = (unsigned short*)take((size_t)2 * 8 * 3 * 2048 * 64 * 2);
  unsigned short* x_bf   = (unsigned short*)take((size_t)2 * 8 * 2048 * 64 * 2);
  (void)ws_size; (void)in_sizes; (void)n_in; (void)out_size;

  prep_cast<<<dim3(2048), dim3(256), 0, stream>>>(query, Wq, Wk, Wv, Wo, tw,
                                                  q_bf, WT_bf, WoT_bf, twT_bf);
  qkv_gemm<<<dim3(32, 24), dim3(256), 0, stream>>>(q_bf, WT_bf, bq, bk, bv,
                                                   qh_bf, kh_bf, vh_bf);
  transpose_v<<<dim3(16, 32), dim3(256), 0, stream>>>(vh_bf, vhT_bf);
  qt_gemm<<<dim3(16, 16, 3), dim3(256), 0, stream>>>(qh_bf, twT_bf, qt_bf);
  flash_attn<<<dim3(128, 2), dim3(512), 0, stream>>>(qt_bf, kh_bf, vhT_bf, tids, bias, x_bf);
  out_gemm<<<dim3(32, 8), dim3(256), 0, stream>>>(x_bf, WoT_bf, bo, out);
}